// Round 8
// baseline (138.235 us; speedup 1.0000x reference)
//
#include <hip/hip_runtime.h>
#include <hip/hip_bf16.h>

// B=8, S=2048, E=1024, H=64. fp32 in/out, bf16 MFMA compute.
// conv_w: W->bf16, PRE-SWIZZLED (16B unit ^= row&7 per 64-elem group).
// qkv_mfma v6 (unchanged from R7): m-tile 32, n=192, 512 blocks x 256 thr,
// BK=64, counted-vmcnt pipeline (raw s_barrier, depth-2 A prefetch,
// depth-1 W glds), XOR-swizzled frag reads.
// attn_mfma v8: DISTINCT-CHUNK loop. lo=p needs chunks 0..p, hi=31-p needs
// 0..31-p (superset) -> iterate distinct chunks once (32-p instead of 33
// staged steps), computing hi every step and lo additionally when c<=p,
// SHARING K-frag and V-frag reads between the two tiles. 28% fewer
// barrier-steps per CU, staging traffic -26%, 2x MFMA per barrier on
// shared chunks. Per-block work is p-dependent; 1D grid decode pairs
// (j, j+8) -> (p, 15-p) so co-resident blocks have complementary loads.
// 4-way chunk parity as before: par0->out/lp0, par k->op[k-1]/lp[k].
// attn_fin: 4-way merge+normalize.

#define BB 8
#define SS 2048
#define EE 1024
#define HH 64
#define MM (BB * SS)

typedef __bf16 bf16;
typedef __attribute__((ext_vector_type(8))) __bf16 bf16x8;
typedef __attribute__((ext_vector_type(4))) __bf16 bf16x4;
typedef __attribute__((ext_vector_type(4))) float f32x4;
typedef __attribute__((ext_vector_type(4))) short short4v;

// global -> LDS direct copy, 16B per lane. LDS dest: wave-uniform base +
// lane*16 (hardware); global src: per-lane address.
__device__ __forceinline__ void glds16(const bf16* g, bf16* l) {
    __builtin_amdgcn_global_load_lds(
        (__attribute__((address_space(1))) const void*)g,
        (__attribute__((address_space(3))) void*)l, 16, 0, 0);
}

// ---------------------------------------------------------------------------
// [Wq;Wk;Wv] (192x1024 fp32) -> Wb (bf16), swizzled: within each 64-elem
// k-group, 8-elem unit u stored at slot u ^ (row&7). 96 blocks.
// ---------------------------------------------------------------------------
__global__ __launch_bounds__(256) void conv_w(const float* __restrict__ Wq,
                                              const float* __restrict__ Wk,
                                              const float* __restrict__ Wv,
                                              bf16* __restrict__ Wb) {
    int i = (blockIdx.x * 256 + threadIdx.x) * 8;
    const float* src;
    int j;
    if (i < 65536)        { src = Wq; j = i; }
    else if (i < 131072)  { src = Wk; j = i - 65536; }
    else                  { src = Wv; j = i - 131072; }
    f32x4 a = *(const f32x4*)(src + j);
    f32x4 b = *(const f32x4*)(src + j + 4);
    bf16x8 o = {(bf16)a.x, (bf16)a.y, (bf16)a.z, (bf16)a.w,
                (bf16)b.x, (bf16)b.y, (bf16)b.z, (bf16)b.w};
    int r   = i >> 10;          // row 0..191
    int kk  = i & 1023;         // element within row (unit-aligned)
    int dst = (r << 10) + (kk & ~63) + ((((kk >> 3) & 7) ^ (r & 7)) << 3);
    *(bf16x8*)(Wb + dst) = o;
}

// ---------------------------------------------------------------------------
// QKV GEMM v6 — counted-vmcnt pipeline (unchanged from R7).
// ---------------------------------------------------------------------------
__global__ __launch_bounds__(256) void qkv_mfma(
    const float* __restrict__ x, const bf16* __restrict__ Wb,
    const float* __restrict__ bq, const float* __restrict__ bk,
    const float* __restrict__ bv,
    bf16* __restrict__ Q, bf16* __restrict__ K, bf16* __restrict__ Vt) {
    __shared__ __align__(16) bf16 As[2][32][64];    // 8 KB, swizzled units
    __shared__ __align__(16) bf16 Ws[2][192][64];   // 48 KB, pre-swizzled

    const int tid  = threadIdx.x;
    const int wave = tid >> 6;
    const int lane = tid & 63;
    const int col  = lane & 15;
    const int quad = lane >> 4;
    const int wm   = wave >> 1;                 // 0..1 (m half, 16 rows)
    const int wn   = wave & 1;                  // 0..1 (n half, 96 cols)
    const int m0   = blockIdx.x * 32;
    const int kph  = (blockIdx.x & 15) << 6;    // k0 phase 0,64,...,960

    const int arow = tid >> 3;
    const int au   = tid & 7;
    const int aoff = au << 3;
    const int asw  = (au ^ (arow & 7)) << 3;
    const int wlr = lane >> 3;                  // row within 8-row segment
    const int wlc = (lane & 7) << 3;            // elem offset of unit

    f32x4 acc[6];
#pragma unroll
    for (int nt = 0; nt < 6; nt++) acc[nt] = {0.f, 0.f, 0.f, 0.f};

#define QSTEP(T, AR, CUR, WAITN)                                              \
    {                                                                         \
        asm volatile("s_waitcnt vmcnt(" #WAITN ")" ::: "memory");             \
        __builtin_amdgcn_sched_barrier(0);                                    \
        bf16x8 a0 = {(bf16)AR[0].x, (bf16)AR[0].y, (bf16)AR[0].z,             \
                     (bf16)AR[0].w, (bf16)AR[1].x, (bf16)AR[1].y,             \
                     (bf16)AR[1].z, (bf16)AR[1].w};                           \
        *(bf16x8*)&As[CUR][arow][asw] = a0;                                   \
        asm volatile("s_waitcnt lgkmcnt(0)" ::: "memory");                    \
        __builtin_amdgcn_sched_barrier(0);                                    \
        __builtin_amdgcn_s_barrier();                                         \
        __builtin_amdgcn_sched_barrier(0);                                    \
        if ((T) + 1 < 16) {                                                   \
            const int kW = (kph + ((T) + 1) * 64) & 1023;                     \
            _Pragma("unroll")                                                 \
            for (int i = 0; i < 6; i++) {                                     \
                const int seg = i * 4 + wave;                                 \
                glds16(&Wb[(size_t)(seg * 8 + wlr) * EE + kW + wlc],          \
                       &Ws[(CUR) ^ 1][seg * 8][0]);                           \
            }                                                                 \
        }                                                                     \
        if ((T) + 2 < 16) {                                                   \
            const int kA = (kph + ((T) + 2) * 64) & 1023;                     \
            _Pragma("unroll")                                                 \
            for (int q = 0; q < 2; q++)                                       \
                AR[q] = *(const f32x4*)&x[(size_t)(m0 + arow) * EE + kA +     \
                                          aoff + q * 4];                      \
        }                                                                     \
        _Pragma("unroll")                                                     \
        for (int kk = 0; kk < 64; kk += 32) {                                 \
            const int ub = (kk >> 3) + quad;                                  \
            const int r  = wm * 16 + col;                                     \
            bf16x8 af = *(const bf16x8*)&As[CUR][r][(ub ^ (r & 7)) << 3];     \
            _Pragma("unroll")                                                 \
            for (int nt = 0; nt < 6; nt++) {                                  \
                int rn = wn * 96 + nt * 16 + col;                             \
                bf16x8 bg =                                                   \
                    *(const bf16x8*)&Ws[CUR][rn][(ub ^ (rn & 7)) << 3];       \
                acc[nt] = __builtin_amdgcn_mfma_f32_16x16x32_bf16(            \
                    af, bg, acc[nt], 0, 0, 0);                                \
            }                                                                 \
        }                                                                     \
    }

    f32x4 arA[2], arB[2];
#pragma unroll
    for (int q = 0; q < 2; q++)
        arA[q] = *(const f32x4*)&x[(size_t)(m0 + arow) * EE + kph + aoff + q * 4];
#pragma unroll
    for (int i = 0; i < 6; i++) {
        const int seg = i * 4 + wave;
        glds16(&Wb[(size_t)(seg * 8 + wlr) * EE + kph + wlc], &Ws[0][seg * 8][0]);
    }
    {
        const int k1 = (kph + 64) & 1023;
#pragma unroll
        for (int q = 0; q < 2; q++)
            arB[q] = *(const f32x4*)&x[(size_t)(m0 + arow) * EE + k1 + aoff + q * 4];
    }

    for (int t = 0; t < 14; t += 2) {
        QSTEP(t, arA, 0, 2)
        QSTEP(t + 1, arB, 1, 2)
    }
    QSTEP(14, arA, 0, 2)
    QSTEP(15, arB, 1, 0)   // tail: no A(17) in flight -> drain fully
#undef QSTEP

    // epilogue: same store math, wave tile 16x96
    {
        const int mr0  = m0 + wm * 16 + quad * 4;
        const int bidx = mr0 >> 11;
        const int sloc = mr0 & 2047;
        const int ck   = sloc >> 6;
        const int so   = sloc & 63;
#pragma unroll
        for (int nt = 0; nt < 6; nt++) {
            const int n = wn * 96 + nt * 16;
            const int g = n >> 6;               // 0=Q 1=K 2=V (unrolled-const)
            const int h = (n & 63) + col;
            if (g == 0) {
                float bias = bq[h];
#pragma unroll
                for (int r = 0; r < 4; r++)
                    Q[(size_t)(mr0 + r) * HH + h] = (bf16)((acc[nt][r] + bias) * 0.125f);
            } else if (g == 1) {
                float bias = bk[h];
#pragma unroll
                for (int r = 0; r < 4; r++) {
                    int s = mr0 + r;                     // swizzled K store
                    int u = (h >> 3) ^ (s & 7);
                    K[(size_t)s * HH + u * 8 + (h & 7)] = (bf16)(acc[nt][r] + bias);
                }
            } else {
                float bias = bv[h];
                bf16x4 pk = {(bf16)(acc[nt][0] + bias), (bf16)(acc[nt][1] + bias),
                             (bf16)(acc[nt][2] + bias), (bf16)(acc[nt][3] + bias)};
                int u = (so >> 3) ^ (h & 7);             // swizzled Vt store
                *(bf16x4*)&Vt[(size_t)bidx * SS * HH + (size_t)ck * 4096 +
                              h * 64 + u * 8 + (so & 7)] = pk;
            }
        }
    }
}

// ---------------------------------------------------------------------------
// Flash attention v8: distinct-chunk loop with shared K/V fragments.
// 1D grid 512: idx -> p (complementary-paired), b, par. Per step: barrier;
// prefetch chunk c+4 via glds; compute hi (always) and lo (c<=p), sharing
// ka/vv fragment reads. Diag masks: lo at c==p, hi at c==31-p.
// ---------------------------------------------------------------------------
__global__ __launch_bounds__(256) void attn_mfma(
    const bf16* __restrict__ Q, const bf16* __restrict__ K,
    const bf16* __restrict__ Vt, float* __restrict__ out,
    float* __restrict__ op, float* __restrict__ lp) {
    __shared__ __align__(16) bf16 kv[2][8192];  // 32 KB: [buf][K 4096 | V 4096]

    const int idx  = blockIdx.x;      // 0..511
    const int ph   = idx & 7;
    const int p    = ((idx >> 3) & 1) ? 15 - ph : ph;  // 0..15, (j,j+8) paired
    const int b    = (idx >> 4) & 7;
    const int par  = idx >> 7;        // 0..3
    const int tid  = threadIdx.x;
    const int wave = tid >> 6;
    const int lane = tid & 63;
    const int col  = lane & 15;
    const int quad = lane >> 4;

    const int cmax = 31 - p;                      // hi chunk range 0..cmax
    const int lo0 = p * 64 + wave * 16;
    const int hi0 = (31 - p) * 64 + wave * 16;

    const bf16* Qb = Q + (size_t)b * SS * HH;
    const bf16* Kb = K + (size_t)b * SS * HH;
    const bf16* Vb = Vt + (size_t)b * SS * HH;

    bf16x8 qlo0 = *(const bf16x8*)&Qb[(size_t)(lo0 + col) * HH + quad * 8];
    bf16x8 qlo1 = *(const bf16x8*)&Qb[(size_t)(lo0 + col) * HH + 32 + quad * 8];
    bf16x8 qhi0 = *(const bf16x8*)&Qb[(size_t)(hi0 + col) * HH + quad * 8];
    bf16x8 qhi1 = *(const bf16x8*)&Qb[(size_t)(hi0 + col) * HH + 32 + quad * 8];

    f32x4 olo[4], ohi[4];
#pragma unroll
    for (int n = 0; n < 4; n++) {
        olo[n] = {0.f, 0.f, 0.f, 0.f};
        ohi[n] = {0.f, 0.f, 0.f, 0.f};
    }
    float llo = 0.f, lhi = 0.f;

#define STAGE(cc, buf)                                                        \
    {                                                                         \
        _Pragma("unroll")                                                     \
        for (int i = 0; i < 4; i++) {                                         \
            const int s = wave * 4 + i;                                       \
            const bf16* g = (s < 8)                                           \
                ? Kb + (size_t)(cc) * 4096 + s * 512 + lane * 8               \
                : Vb + (size_t)(cc) * 4096 + (s - 8) * 512 + lane * 8;        \
            glds16(g, &kv[buf][s * 512]);                                     \
        }                                                                     \
    }

    STAGE(par, 0);

    int sidx = 0;
    for (int c = par; c <= cmax; c += 4, sidx++) {
        const int cur = sidx & 1;

        __syncthreads();  // drains glds: kv[cur] complete & visible

        if (c + 4 <= cmax) STAGE(c + 4, cur ^ 1);

        const bf16* lk = &kv[cur][0];
        const bf16* lv = &kv[cur][4096];
        const bool doLo = (c <= p);

        // QK^T, K-fragments shared between hi and lo
        f32x4 shi[4], slo[4];
#pragma unroll
        for (int n4 = 0; n4 < 4; n4++) {
            int sr = n4 * 16 + col;
            bf16x8 ka0 = *(const bf16x8*)&lk[sr * 64 + ((quad ^ (sr & 7)) * 8)];
            bf16x8 ka1 = *(const bf16x8*)&lk[sr * 64 + (((4 + quad) ^ (sr & 7)) * 8)];
            f32x4 z = {0.f, 0.f, 0.f, 0.f};
            z       = __builtin_amdgcn_mfma_f32_16x16x32_bf16(ka0, qhi0, z, 0, 0, 0);
            shi[n4] = __builtin_amdgcn_mfma_f32_16x16x32_bf16(ka1, qhi1, z, 0, 0, 0);
            if (doLo) {
                f32x4 z2 = {0.f, 0.f, 0.f, 0.f};
                z2      = __builtin_amdgcn_mfma_f32_16x16x32_bf16(ka0, qlo0, z2, 0, 0, 0);
                slo[n4] = __builtin_amdgcn_mfma_f32_16x16x32_bf16(ka1, qlo1, z2, 0, 0, 0);
            }
        }

        // softmax (fixed-max additive), hi always, lo when active
        float rshi = 0.f, rslo = 0.f;
        short4v p4hi[4], p4lo[4];
        {
            const bool dg = (c == cmax);
            const int  qr = hi0 + col;
#pragma unroll
            for (int n4 = 0; n4 < 4; n4++) {
                bf16x4 pb;
#pragma unroll
                for (int r = 0; r < 4; r++) {
                    float pe = __expf(shi[n4][r]);
                    if (dg) {
                        int kr = c * 64 + n4 * 16 + quad * 4 + r;
                        if (kr > qr) pe = 0.f;
                    }
                    rshi += pe;
                    pb[r] = (bf16)pe;
                }
                p4hi[n4] = __builtin_bit_cast(short4v, pb);
            }
        }
        if (doLo) {
            const bool dg = (c == p);
            const int  qr = lo0 + col;
#pragma unroll
            for (int n4 = 0; n4 < 4; n4++) {
                bf16x4 pb;
#pragma unroll
                for (int r = 0; r < 4; r++) {
                    float pe = __expf(slo[n4][r]);
                    if (dg) {
                        int kr = c * 64 + n4 * 16 + quad * 4 + r;
                        if (kr > qr) pe = 0.f;
                    }
                    rslo += pe;
                    pb[r] = (bf16)pe;
                }
                p4lo[n4] = __builtin_bit_cast(short4v, pb);
            }
        }
        lhi += rshi;
        if (doLo) llo += rslo;

        // PV, V-fragments shared between hi and lo
#pragma unroll
        for (int h4 = 0; h4 < 4; h4++)
#pragma unroll
            for (int n4 = 0; n4 < 4; n4++) {
                int vr = h4 * 16 + col;
                int u  = n4 * 2 + (quad >> 1);
                bf16x4 vv = *(const bf16x4*)&lv[vr * 64 + ((u ^ (vr & 7)) * 8) +
                                                (quad & 1) * 4];
                short4v vs = __builtin_bit_cast(short4v, vv);
                ohi[h4] = __builtin_amdgcn_mfma_f32_16x16x16bf16_1k(
                    p4hi[n4], vs, ohi[h4], 0, 0, 0);
                if (doLo)
                    olo[h4] = __builtin_amdgcn_mfma_f32_16x16x16bf16_1k(
                        p4lo[n4], vs, olo[h4], 0, 0, 0);
            }
    }
#undef STAGE

    // l: reduce across the 4 quads (same q = col); direct global partials
    llo += __shfl_xor(llo, 16); llo += __shfl_xor(llo, 32);
    lhi += __shfl_xor(lhi, 16); lhi += __shfl_xor(lhi, 32);
    float* od = par ? op + (size_t)(par - 1) * MM * HH : out;
    float* ld = lp + (size_t)par * MM;
    if (quad == 0) {
        ld[b * SS + lo0 + col] = llo;
        ld[b * SS + hi0 + col] = lhi;
    }
#pragma unroll
    for (int h4 = 0; h4 < 4; h4++)
#pragma unroll
        for (int r = 0; r < 4; r++) {
            od[((size_t)b * SS + lo0 + quad * 4 + r) * HH + h4 * 16 + col] = olo[h4][r];
            od[((size_t)b * SS + hi0 + quad * 4 + r) * HH + h4 * 16 + col] = ohi[h4][r];
        }
}

// ---------------------------------------------------------------------------
// Merge 4 parity partials: out = (out + op0 + op1 + op2) / (sum lp). 1024 bl.
// ---------------------------------------------------------------------------
__global__ __launch_bounds__(256) void attn_fin(float* __restrict__ out,
                                                const float* __restrict__ op,
                                                const float* __restrict__ lp) {
    int i   = blockIdx.x * 256 + threadIdx.x;  // f32x4 index, 262144 total
    int row = i >> 4;
    float inv = 1.f / (lp[row] + lp[MM + row] + lp[2 * MM + row] + lp[3 * MM + row]);
    f32x4 a = *(f32x4*)&out[i * 4];
    a += *(const f32x4*)&op[i * 4];
    a += *(const f32x4*)&op[(size_t)MM * HH + i * 4];
    a += *(const f32x4*)&op[(size_t)2 * MM * HH + i * 4];
    a *= inv;
    *(f32x4*)&out[i * 4] = a;
}

extern "C" void kernel_launch(void* const* d_in, const int* in_sizes, int n_in,
                              void* d_out, int out_size, void* d_ws, size_t ws_size,
                              hipStream_t stream) {
    const float* x  = (const float*)d_in[0];
    const float* Wq = (const float*)d_in[1];
    const float* bq = (const float*)d_in[2];
    const float* Wk = (const float*)d_in[3];
    const float* bk = (const float*)d_in[4];
    const float* Wv = (const float*)d_in[5];
    const float* bv = (const float*)d_in[6];
    float* out = (float*)d_out;

    bf16*  Q  = (bf16*)d_ws;                   // 2 MB
    bf16*  K  = Q + (size_t)MM * HH;           // 2 MB (swizzled)
    bf16*  Vt = K + (size_t)MM * HH;           // 2 MB (chunk-tiled, swizzled)
    bf16*  Wb = Vt + (size_t)MM * HH;          // 384 KB (pre-swizzled)
    float* op = (float*)(Wb + (size_t)192 * EE);  // 12 MB (par1..3 partial o)
    float* lp = op + (size_t)3 * MM * HH;      // 256 KB (par0..3 partial l)

    conv_w<<<96, 256, 0, stream>>>(Wq, Wk, Wv, Wb);
    qkv_mfma<<<MM / 32, 256, 0, stream>>>(x, Wb, bq, bk, bv, Q, K, Vt);
    attn_mfma<<<512, 256, 0, stream>>>(Q, K, Vt, out, op, lp);
    attn_fin<<<1024, 256, 0, stream>>>(out, op, lp);
}

// Round 9
// 137.063 us; speedup vs baseline: 1.0086x; 1.0086x over previous
//
#include <hip/hip_runtime.h>
#include <hip/hip_bf16.h>

// B=8, S=2048, E=1024, H=64. fp32 in/out, bf16 MFMA compute.
// conv_w: W->bf16, PRE-SWIZZLED (16B unit ^= row&7 per 64-elem group).
// qkv_mfma v7: R2's best-measured geometry (m-tile 64, n=192, 256 blocks x
// 512 thr, 8 waves 2x4 grid, wave tile 32x48) + R7's counted-vmcnt glds
// pipeline. Halves the Wb broadcast traffic vs m-tile 32 (96 MB vs 192 MB
// chip-wide) -- the only traffic-level lever left; schedule changes R4-R7
// were all flat. Per-thread queue [A(t):2, W(t):3, A(t+1):2] -> vmcnt(2),
// raw s_barrier, depth-2 A prefetch, depth-1 W glds, tail vmcnt(0).
// attn_mfma v8 (unchanged): distinct-chunk loop, shared K/V frags, 4-way
// parity, complementary-paired 1D grid. attn_fin: 4-way merge+normalize.

#define BB 8
#define SS 2048
#define EE 1024
#define HH 64
#define MM (BB * SS)

typedef __bf16 bf16;
typedef __attribute__((ext_vector_type(8))) __bf16 bf16x8;
typedef __attribute__((ext_vector_type(4))) __bf16 bf16x4;
typedef __attribute__((ext_vector_type(4))) float f32x4;
typedef __attribute__((ext_vector_type(4))) short short4v;

// global -> LDS direct copy, 16B per lane. LDS dest: wave-uniform base +
// lane*16 (hardware); global src: per-lane address.
__device__ __forceinline__ void glds16(const bf16* g, bf16* l) {
    __builtin_amdgcn_global_load_lds(
        (__attribute__((address_space(1))) const void*)g,
        (__attribute__((address_space(3))) void*)l, 16, 0, 0);
}

// ---------------------------------------------------------------------------
// [Wq;Wk;Wv] (192x1024 fp32) -> Wb (bf16), swizzled: within each 64-elem
// k-group, 8-elem unit u stored at slot u ^ (row&7). 96 blocks.
// ---------------------------------------------------------------------------
__global__ __launch_bounds__(256) void conv_w(const float* __restrict__ Wq,
                                              const float* __restrict__ Wk,
                                              const float* __restrict__ Wv,
                                              bf16* __restrict__ Wb) {
    int i = (blockIdx.x * 256 + threadIdx.x) * 8;
    const float* src;
    int j;
    if (i < 65536)        { src = Wq; j = i; }
    else if (i < 131072)  { src = Wk; j = i - 65536; }
    else                  { src = Wv; j = i - 131072; }
    f32x4 a = *(const f32x4*)(src + j);
    f32x4 b = *(const f32x4*)(src + j + 4);
    bf16x8 o = {(bf16)a.x, (bf16)a.y, (bf16)a.z, (bf16)a.w,
                (bf16)b.x, (bf16)b.y, (bf16)b.z, (bf16)b.w};
    int r   = i >> 10;          // row 0..191
    int kk  = i & 1023;         // element within row (unit-aligned)
    int dst = (r << 10) + (kk & ~63) + ((((kk >> 3) & 7) ^ (r & 7)) << 3);
    *(bf16x8*)(Wb + dst) = o;
}

// ---------------------------------------------------------------------------
// QKV GEMM v7 — 64-tile geometry, counted-vmcnt pipeline.
// Block = 512 thr (8 waves, 2x4 grid, wave tile 32x48), m-tile 64, n=192,
// BK=64, 16 K-steps; 256 blocks = 1/CU, LDS 64KB (As 16 + Ws 48).
// ---------------------------------------------------------------------------
__global__ __launch_bounds__(512) void qkv_mfma(
    const float* __restrict__ x, const bf16* __restrict__ Wb,
    const float* __restrict__ bq, const float* __restrict__ bk,
    const float* __restrict__ bv,
    bf16* __restrict__ Q, bf16* __restrict__ K, bf16* __restrict__ Vt) {
    __shared__ __align__(16) bf16 As[2][64][64];    // 16 KB, swizzled units
    __shared__ __align__(16) bf16 Ws[2][192][64];   // 48 KB, pre-swizzled

    const int tid  = threadIdx.x;
    const int wave = tid >> 6;
    const int lane = tid & 63;
    const int col  = lane & 15;
    const int quad = lane >> 4;
    const int wm   = wave >> 2;                 // 0..1 (m half, 32 rows)
    const int wn   = wave & 3;                  // 0..3 (n quarter, 48 cols)
    const int m0   = blockIdx.x * 64;
    const int kph  = (blockIdx.x & 15) << 6;    // k0 phase 0,64,...,960

    // A staging: thread t -> row t>>3 (0..63), unit t&7 (8 fp32)
    const int arow = tid >> 3;
    const int au   = tid & 7;
    const int aoff = au << 3;
    const int asw  = (au ^ (arow & 7)) << 3;
    // W glds lane mapping: wave stages segs {wave, wave+8, wave+16}
    const int wlr = lane >> 3;                  // row within 8-row segment
    const int wlc = (lane & 7) << 3;            // elem offset of unit

    f32x4 acc[2][3];
#pragma unroll
    for (int mt = 0; mt < 2; mt++)
#pragma unroll
        for (int nt = 0; nt < 3; nt++) acc[mt][nt] = {0.f, 0.f, 0.f, 0.f};

    // pipeline step: wait batch(T) [vmcnt(WAITN)], commit A, raw barrier,
    // issue W(T+1) glds + A(T+2) loads, compute. CUR = T&1 (literal).
#define QSTEP(T, AR, CUR, WAITN)                                              \
    {                                                                         \
        asm volatile("s_waitcnt vmcnt(" #WAITN ")" ::: "memory");             \
        __builtin_amdgcn_sched_barrier(0);                                    \
        bf16x8 a0 = {(bf16)AR[0].x, (bf16)AR[0].y, (bf16)AR[0].z,             \
                     (bf16)AR[0].w, (bf16)AR[1].x, (bf16)AR[1].y,             \
                     (bf16)AR[1].z, (bf16)AR[1].w};                           \
        *(bf16x8*)&As[CUR][arow][asw] = a0;                                   \
        asm volatile("s_waitcnt lgkmcnt(0)" ::: "memory");                    \
        __builtin_amdgcn_sched_barrier(0);                                    \
        __builtin_amdgcn_s_barrier();                                         \
        __builtin_amdgcn_sched_barrier(0);                                    \
        if ((T) + 1 < 16) {                                                   \
            const int kW = (kph + ((T) + 1) * 64) & 1023;                     \
            _Pragma("unroll")                                                 \
            for (int i = 0; i < 3; i++) {                                     \
                const int seg = i * 8 + wave;                                 \
                glds16(&Wb[(size_t)(seg * 8 + wlr) * EE + kW + wlc],          \
                       &Ws[(CUR) ^ 1][seg * 8][0]);                           \
            }                                                                 \
        }                                                                     \
        if ((T) + 2 < 16) {                                                   \
            const int kA = (kph + ((T) + 2) * 64) & 1023;                     \
            _Pragma("unroll")                                                 \
            for (int q = 0; q < 2; q++)                                       \
                AR[q] = *(const f32x4*)&x[(size_t)(m0 + arow) * EE + kA +     \
                                          aoff + q * 4];                      \
        }                                                                     \
        _Pragma("unroll")                                                     \
        for (int kk = 0; kk < 64; kk += 32) {                                 \
            const int ub = (kk >> 3) + quad;                                  \
            bf16x8 af[2];                                                     \
            _Pragma("unroll")                                                 \
            for (int mt = 0; mt < 2; mt++) {                                  \
                const int r = wm * 32 + mt * 16 + col;                        \
                af[mt] = *(const bf16x8*)&As[CUR][r][(ub ^ (r & 7)) << 3];    \
            }                                                                 \
            _Pragma("unroll")                                                 \
            for (int nt = 0; nt < 3; nt++) {                                  \
                int rn = wn * 48 + nt * 16 + col;                             \
                bf16x8 bg =                                                   \
                    *(const bf16x8*)&Ws[CUR][rn][(ub ^ (rn & 7)) << 3];       \
                acc[0][nt] = __builtin_amdgcn_mfma_f32_16x16x32_bf16(         \
                    af[0], bg, acc[0][nt], 0, 0, 0);                          \
                acc[1][nt] = __builtin_amdgcn_mfma_f32_16x16x32_bf16(         \
                    af[1], bg, acc[1][nt], 0, 0, 0);                          \
            }                                                                 \
        }                                                                     \
    }

    // prologue: A(0)->arA, W(0)->Ws[0], A(1)->arB  (queue order A0,W0,A1)
    f32x4 arA[2], arB[2];
#pragma unroll
    for (int q = 0; q < 2; q++)
        arA[q] = *(const f32x4*)&x[(size_t)(m0 + arow) * EE + kph + aoff + q * 4];
#pragma unroll
    for (int i = 0; i < 3; i++) {
        const int seg = i * 8 + wave;
        glds16(&Wb[(size_t)(seg * 8 + wlr) * EE + kph + wlc], &Ws[0][seg * 8][0]);
    }
    {
        const int k1 = (kph + 64) & 1023;
#pragma unroll
        for (int q = 0; q < 2; q++)
            arB[q] = *(const f32x4*)&x[(size_t)(m0 + arow) * EE + k1 + aoff + q * 4];
    }

    for (int t = 0; t < 14; t += 2) {
        QSTEP(t, arA, 0, 2)
        QSTEP(t + 1, arB, 1, 2)
    }
    QSTEP(14, arA, 0, 2)
    QSTEP(15, arB, 1, 0)   // tail: no A(17) in flight -> drain fully
#undef QSTEP

    // epilogue: R2's verified store math, 2x4 wave-grid ownership
#pragma unroll
    for (int mt = 0; mt < 2; mt++) {
        const int mr0  = m0 + wm * 32 + mt * 16 + quad * 4;
        const int bidx = mr0 >> 11;
        const int sloc = mr0 & 2047;
        const int ck   = sloc >> 6;
        const int so   = sloc & 63;
#pragma unroll
        for (int nt = 0; nt < 3; nt++) {
            const int n = wn * 48 + nt * 16;
            const int g = n >> 6;               // 0=Q 1=K 2=V (unrolled-const)
            const int h = (n & 63) + col;
            if (g == 0) {
                float bias = bq[h];
#pragma unroll
                for (int r = 0; r < 4; r++)
                    Q[(size_t)(mr0 + r) * HH + h] = (bf16)((acc[mt][nt][r] + bias) * 0.125f);
            } else if (g == 1) {
                float bias = bk[h];
#pragma unroll
                for (int r = 0; r < 4; r++) {
                    int s = mr0 + r;                     // swizzled K store
                    int u = (h >> 3) ^ (s & 7);
                    K[(size_t)s * HH + u * 8 + (h & 7)] = (bf16)(acc[mt][nt][r] + bias);
                }
            } else {
                float bias = bv[h];
                bf16x4 pk = {(bf16)(acc[mt][nt][0] + bias), (bf16)(acc[mt][nt][1] + bias),
                             (bf16)(acc[mt][nt][2] + bias), (bf16)(acc[mt][nt][3] + bias)};
                int u = (so >> 3) ^ (h & 7);             // swizzled Vt store
                *(bf16x4*)&Vt[(size_t)bidx * SS * HH + (size_t)ck * 4096 +
                              h * 64 + u * 8 + (so & 7)] = pk;
            }
        }
    }
}

// ---------------------------------------------------------------------------
// Flash attention v8 (unchanged): distinct-chunk loop, shared K/V frags.
// ---------------------------------------------------------------------------
__global__ __launch_bounds__(256) void attn_mfma(
    const bf16* __restrict__ Q, const bf16* __restrict__ K,
    const bf16* __restrict__ Vt, float* __restrict__ out,
    float* __restrict__ op, float* __restrict__ lp) {
    __shared__ __align__(16) bf16 kv[2][8192];  // 32 KB: [buf][K 4096 | V 4096]

    const int idx  = blockIdx.x;      // 0..511
    const int ph   = idx & 7;
    const int p    = ((idx >> 3) & 1) ? 15 - ph : ph;  // 0..15, (j,j+8) paired
    const int b    = (idx >> 4) & 7;
    const int par  = idx >> 7;        // 0..3
    const int tid  = threadIdx.x;
    const int wave = tid >> 6;
    const int lane = tid & 63;
    const int col  = lane & 15;
    const int quad = lane >> 4;

    const int cmax = 31 - p;                      // hi chunk range 0..cmax
    const int lo0 = p * 64 + wave * 16;
    const int hi0 = (31 - p) * 64 + wave * 16;

    const bf16* Qb = Q + (size_t)b * SS * HH;
    const bf16* Kb = K + (size_t)b * SS * HH;
    const bf16* Vb = Vt + (size_t)b * SS * HH;

    bf16x8 qlo0 = *(const bf16x8*)&Qb[(size_t)(lo0 + col) * HH + quad * 8];
    bf16x8 qlo1 = *(const bf16x8*)&Qb[(size_t)(lo0 + col) * HH + 32 + quad * 8];
    bf16x8 qhi0 = *(const bf16x8*)&Qb[(size_t)(hi0 + col) * HH + quad * 8];
    bf16x8 qhi1 = *(const bf16x8*)&Qb[(size_t)(hi0 + col) * HH + 32 + quad * 8];

    f32x4 olo[4], ohi[4];
#pragma unroll
    for (int n = 0; n < 4; n++) {
        olo[n] = {0.f, 0.f, 0.f, 0.f};
        ohi[n] = {0.f, 0.f, 0.f, 0.f};
    }
    float llo = 0.f, lhi = 0.f;

#define STAGE(cc, buf)                                                        \
    {                                                                         \
        _Pragma("unroll")                                                     \
        for (int i = 0; i < 4; i++) {                                         \
            const int s = wave * 4 + i;                                       \
            const bf16* g = (s < 8)                                           \
                ? Kb + (size_t)(cc) * 4096 + s * 512 + lane * 8               \
                : Vb + (size_t)(cc) * 4096 + (s - 8) * 512 + lane * 8;        \
            glds16(g, &kv[buf][s * 512]);                                     \
        }                                                                     \
    }

    STAGE(par, 0);

    int sidx = 0;
    for (int c = par; c <= cmax; c += 4, sidx++) {
        const int cur = sidx & 1;

        __syncthreads();  // drains glds: kv[cur] complete & visible

        if (c + 4 <= cmax) STAGE(c + 4, cur ^ 1);

        const bf16* lk = &kv[cur][0];
        const bf16* lv = &kv[cur][4096];
        const bool doLo = (c <= p);

        // QK^T, K-fragments shared between hi and lo
        f32x4 shi[4], slo[4];
#pragma unroll
        for (int n4 = 0; n4 < 4; n4++) {
            int sr = n4 * 16 + col;
            bf16x8 ka0 = *(const bf16x8*)&lk[sr * 64 + ((quad ^ (sr & 7)) * 8)];
            bf16x8 ka1 = *(const bf16x8*)&lk[sr * 64 + (((4 + quad) ^ (sr & 7)) * 8)];
            f32x4 z = {0.f, 0.f, 0.f, 0.f};
            z       = __builtin_amdgcn_mfma_f32_16x16x32_bf16(ka0, qhi0, z, 0, 0, 0);
            shi[n4] = __builtin_amdgcn_mfma_f32_16x16x32_bf16(ka1, qhi1, z, 0, 0, 0);
            if (doLo) {
                f32x4 z2 = {0.f, 0.f, 0.f, 0.f};
                z2      = __builtin_amdgcn_mfma_f32_16x16x32_bf16(ka0, qlo0, z2, 0, 0, 0);
                slo[n4] = __builtin_amdgcn_mfma_f32_16x16x32_bf16(ka1, qlo1, z2, 0, 0, 0);
            }
        }

        // softmax (fixed-max additive), hi always, lo when active
        float rshi = 0.f, rslo = 0.f;
        short4v p4hi[4], p4lo[4];
        {
            const bool dg = (c == cmax);
            const int  qr = hi0 + col;
#pragma unroll
            for (int n4 = 0; n4 < 4; n4++) {
                bf16x4 pb;
#pragma unroll
                for (int r = 0; r < 4; r++) {
                    float pe = __expf(shi[n4][r]);
                    if (dg) {
                        int kr = c * 64 + n4 * 16 + quad * 4 + r;
                        if (kr > qr) pe = 0.f;
                    }
                    rshi += pe;
                    pb[r] = (bf16)pe;
                }
                p4hi[n4] = __builtin_bit_cast(short4v, pb);
            }
        }
        if (doLo) {
            const bool dg = (c == p);
            const int  qr = lo0 + col;
#pragma unroll
            for (int n4 = 0; n4 < 4; n4++) {
                bf16x4 pb;
#pragma unroll
                for (int r = 0; r < 4; r++) {
                    float pe = __expf(slo[n4][r]);
                    if (dg) {
                        int kr = c * 64 + n4 * 16 + quad * 4 + r;
                        if (kr > qr) pe = 0.f;
                    }
                    rslo += pe;
                    pb[r] = (bf16)pe;
                }
                p4lo[n4] = __builtin_bit_cast(short4v, pb);
            }
        }
        lhi += rshi;
        if (doLo) llo += rslo;

        // PV, V-fragments shared between hi and lo
#pragma unroll
        for (int h4 = 0; h4 < 4; h4++)
#pragma unroll
            for (int n4 = 0; n4 < 4; n4++) {
                int vr = h4 * 16 + col;
                int u  = n4 * 2 + (quad >> 1);
                bf16x4 vv = *(const bf16x4*)&lv[vr * 64 + ((u ^ (vr & 7)) * 8) +
                                                (quad & 1) * 4];
                short4v vs = __builtin_bit_cast(short4v, vv);
                ohi[h4] = __builtin_amdgcn_mfma_f32_16x16x16bf16_1k(
                    p4hi[n4], vs, ohi[h4], 0, 0, 0);
                if (doLo)
                    olo[h4] = __builtin_amdgcn_mfma_f32_16x16x16bf16_1k(
                        p4lo[n4], vs, olo[h4], 0, 0, 0);
            }
    }
#undef STAGE

    // l: reduce across the 4 quads (same q = col); direct global partials
    llo += __shfl_xor(llo, 16); llo += __shfl_xor(llo, 32);
    lhi += __shfl_xor(lhi, 16); lhi += __shfl_xor(lhi, 32);
    float* od = par ? op + (size_t)(par - 1) * MM * HH : out;
    float* ld = lp + (size_t)par * MM;
    if (quad == 0) {
        ld[b * SS + lo0 + col] = llo;
        ld[b * SS + hi0 + col] = lhi;
    }
#pragma unroll
    for (int h4 = 0; h4 < 4; h4++)
#pragma unroll
        for (int r = 0; r < 4; r++) {
            od[((size_t)b * SS + lo0 + quad * 4 + r) * HH + h4 * 16 + col] = olo[h4][r];
            od[((size_t)b * SS + hi0 + quad * 4 + r) * HH + h4 * 16 + col] = ohi[h4][r];
        }
}

// ---------------------------------------------------------------------------
// Merge 4 parity partials: out = (out + op0 + op1 + op2) / (sum lp). 1024 bl.
// ---------------------------------------------------------------------------
__global__ __launch_bounds__(256) void attn_fin(float* __restrict__ out,
                                                const float* __restrict__ op,
                                                const float* __restrict__ lp) {
    int i   = blockIdx.x * 256 + threadIdx.x;  // f32x4 index, 262144 total
    int row = i >> 4;
    float inv = 1.f / (lp[row] + lp[MM + row] + lp[2 * MM + row] + lp[3 * MM + row]);
    f32x4 a = *(f32x4*)&out[i * 4];
    a += *(const f32x4*)&op[i * 4];
    a += *(const f32x4*)&op[(size_t)MM * HH + i * 4];
    a += *(const f32x4*)&op[(size_t)2 * MM * HH + i * 4];
    a *= inv;
    *(f32x4*)&out[i * 4] = a;
}

extern "C" void kernel_launch(void* const* d_in, const int* in_sizes, int n_in,
                              void* d_out, int out_size, void* d_ws, size_t ws_size,
                              hipStream_t stream) {
    const float* x  = (const float*)d_in[0];
    const float* Wq = (const float*)d_in[1];
    const float* bq = (const float*)d_in[2];
    const float* Wk = (const float*)d_in[3];
    const float* bk = (const float*)d_in[4];
    const float* Wv = (const float*)d_in[5];
    const float* bv = (const float*)d_in[6];
    float* out = (float*)d_out;

    bf16*  Q  = (bf16*)d_ws;                   // 2 MB
    bf16*  K  = Q + (size_t)MM * HH;           // 2 MB (swizzled)
    bf16*  Vt = K + (size_t)MM * HH;           // 2 MB (chunk-tiled, swizzled)
    bf16*  Wb = Vt + (size_t)MM * HH;          // 384 KB (pre-swizzled)
    float* op = (float*)(Wb + (size_t)192 * EE);  // 12 MB (par1..3 partial o)
    float* lp = op + (size_t)3 * MM * HH;      // 256 KB (par0..3 partial l)

    conv_w<<<96, 256, 0, stream>>>(Wq, Wk, Wv, Wb);
    qkv_mfma<<<MM / 64, 512, 0, stream>>>(x, Wb, bq, bk, bv, Q, K, Vt);
    attn_mfma<<<512, 256, 0, stream>>>(Q, K, Vt, out, op, lp);
    attn_fin<<<1024, 256, 0, stream>>>(out, op, lp);
}